// Round 1
// baseline (463.475 us; speedup 1.0000x reference)
//
#include <hip/hip_runtime.h>
#include <hip/hip_bf16.h>

#define B_    4
#define L_    2048
#define T_    8192      // B*L tokens
#define D_    1024
#define E_    8
#define H_    512

typedef __bf16  bf16x8 __attribute__((ext_vector_type(8)));
typedef float   f32x4  __attribute__((ext_vector_type(4)));
typedef unsigned short u16x8 __attribute__((ext_vector_type(8)));
typedef unsigned short ushort_t;

__device__ __forceinline__ ushort_t f2bf(float f) {
    union { float f; unsigned u; } v; v.f = f;
    unsigned u = v.u;
    // round-to-nearest-even to bf16
    unsigned r = (u + 0x7fffu + ((u >> 16) & 1u)) >> 16;
    return (ushort_t)r;
}

__device__ __forceinline__ float gelu_exact(float v) {
    return 0.5f * v * (1.0f + erff(v * 0.70710678118654752f));
}

// ---------------------------------------------------------------------------
// Transpose + fp32->bf16 convert:  in [nmat][R][C] f32  ->  out [nmat][C][R] bf16
// grid: (C/32, R/32, nmat), block: 256
// ---------------------------------------------------------------------------
__global__ __launch_bounds__(256) void transpose_cvt(
    const float* __restrict__ in, ushort_t* __restrict__ out, int R, int C)
{
    __shared__ float tile[32][33];
    const size_t matoff = (size_t)blockIdx.z * R * C;
    const float* src = in + matoff;
    ushort_t* dst = out + matoff;
    const int r0 = blockIdx.y * 32, c0 = blockIdx.x * 32;
    const int tid = threadIdx.x;
    const int lr = tid >> 3;          // 0..31
    const int lc = (tid & 7) * 4;     // 0..28
    float4 v = *(const float4*)(src + (size_t)(r0 + lr) * C + c0 + lc);
    tile[lr][lc+0] = v.x; tile[lr][lc+1] = v.y;
    tile[lr][lc+2] = v.z; tile[lr][lc+3] = v.w;
    __syncthreads();
    ushort4 o;
    o.x = f2bf(tile[lc+0][lr]);
    o.y = f2bf(tile[lc+1][lr]);
    o.z = f2bf(tile[lc+2][lr]);
    o.w = f2bf(tile[lc+3][lr]);
    *(ushort4*)(dst + (size_t)(c0 + lr) * R + r0 + lc) = o;
}

// ---------------------------------------------------------------------------
// Gating: fp32 logits, top-2, softmax, bucket append. One wave per token.
// ---------------------------------------------------------------------------
__global__ __launch_bounds__(64) void gating_kernel(
    const float* __restrict__ x, const float* __restrict__ gw,
    const float* __restrict__ gb,
    int* __restrict__ counts, int* __restrict__ btok, float* __restrict__ bgate)
{
    const int t = blockIdx.x;
    const int lane = threadIdx.x;
    const float* xr = x + (size_t)t * D_;

    float acc[E_];
    #pragma unroll
    for (int e = 0; e < E_; ++e) acc[e] = 0.f;

    #pragma unroll
    for (int j = 0; j < 4; ++j) {
        const int d = j * 256 + lane * 4;
        float4 xv = *(const float4*)(xr + d);
        const float* gr = gw + (size_t)d * E_;
        float xs[4] = {xv.x, xv.y, xv.z, xv.w};
        #pragma unroll
        for (int c = 0; c < 4; ++c) {
            float4 g0 = *(const float4*)(gr + c * 8);
            float4 g1 = *(const float4*)(gr + c * 8 + 4);
            acc[0] += xs[c] * g0.x; acc[1] += xs[c] * g0.y;
            acc[2] += xs[c] * g0.z; acc[3] += xs[c] * g0.w;
            acc[4] += xs[c] * g1.x; acc[5] += xs[c] * g1.y;
            acc[6] += xs[c] * g1.z; acc[7] += xs[c] * g1.w;
        }
    }
    #pragma unroll
    for (int s = 1; s < 64; s <<= 1) {
        #pragma unroll
        for (int e = 0; e < E_; ++e)
            acc[e] += __shfl_xor(acc[e], s, 64);
    }
    if (lane == 0) {
        float v[E_];
        #pragma unroll
        for (int e = 0; e < E_; ++e) v[e] = acc[e] + gb[e];
        int i0 = 0;
        #pragma unroll
        for (int e = 1; e < E_; ++e) if (v[e] > v[i0]) i0 = e;   // ties -> lowest idx
        int i1 = (i0 == 0) ? 1 : 0;
        #pragma unroll
        for (int e = 0; e < E_; ++e) if (e != i0 && v[e] > v[i1]) i1 = e;
        float g0 = 1.f / (1.f + expf(v[i1] - v[i0]));  // softmax over top-2
        float g1 = 1.f - g0;
        int p0 = atomicAdd(&counts[i0], 1);
        btok[i0 * T_ + p0] = t; bgate[i0 * T_ + p0] = g0;
        int p1 = atomicAdd(&counts[i1], 1);
        btok[i1 * T_ + p1] = t; bgate[i1 * T_ + p1] = g1;
    }
}

__global__ void prefix_kernel(const int* __restrict__ counts, int* __restrict__ offsets)
{
    if (threadIdx.x == 0 && blockIdx.x == 0) {
        int s = 0;
        for (int e = 0; e < E_; ++e) { offsets[e] = s; s += counts[e]; }
    }
}

// ---------------------------------------------------------------------------
// Layer 1: per expert, gathered X [n_e,1024] @ W1t[e] -> gelu -> hbuf bf16
// tiles 64x64x64, 256 thr = 4 waves, wave computes 32x32 (2x2 16x16x32 MFMA)
// grid: (128, H/64=8, E)
// ---------------------------------------------------------------------------
__global__ __launch_bounds__(256) void mlp1_kernel(
    const float* __restrict__ x, const ushort_t* __restrict__ w1t,
    const float* __restrict__ b1,
    const int* __restrict__ counts, const int* __restrict__ offsets,
    const int* __restrict__ btok, ushort_t* __restrict__ hbuf)
{
    const int e   = blockIdx.z;
    const int n_e = counts[e];
    const int m0  = blockIdx.x * 64;
    if (m0 >= n_e) return;
    const int n0  = blockIdx.y * 64;
    const int off = offsets[e];

    __shared__ ushort_t As[64][72];   // +8 pad: 2-way bank alias only (free)
    __shared__ ushort_t Bs[64][72];
    __shared__ int toks[64];

    const int tid = threadIdx.x;
    if (tid < 64) {
        int m = m0 + tid;
        toks[tid] = btok[e * T_ + (m < n_e ? m : n_e - 1)];
    }
    __syncthreads();

    const ushort_t* w1e = w1t + (size_t)e * (H_ * D_);   // [H][D] bf16

    const int lr = tid >> 2;          // staging row 0..63
    const int lc = (tid & 3) * 16;    // staging col group

    const int lane = tid & 63;
    const int wave = tid >> 6;
    const int wm = (wave & 1) * 32;
    const int wn = (wave >> 1) * 32;
    const int fm = lane & 15;
    const int fk = (lane >> 4) * 8;

    f32x4 acc[2][2];
    #pragma unroll
    for (int i = 0; i < 2; ++i)
        #pragma unroll
        for (int j = 0; j < 2; ++j)
            { acc[i][j][0]=0.f; acc[i][j][1]=0.f; acc[i][j][2]=0.f; acc[i][j][3]=0.f; }

    const float* xrow = x + (size_t)toks[lr] * D_;

    for (int k0 = 0; k0 < D_; k0 += 64) {
        // stage A (gather + fp32->bf16)
        float4 v0 = *(const float4*)(xrow + k0 + lc);
        float4 v1 = *(const float4*)(xrow + k0 + lc + 4);
        float4 v2 = *(const float4*)(xrow + k0 + lc + 8);
        float4 v3 = *(const float4*)(xrow + k0 + lc + 12);
        u16x8 p0, p1;
        p0[0]=f2bf(v0.x); p0[1]=f2bf(v0.y); p0[2]=f2bf(v0.z); p0[3]=f2bf(v0.w);
        p0[4]=f2bf(v1.x); p0[5]=f2bf(v1.y); p0[6]=f2bf(v1.z); p0[7]=f2bf(v1.w);
        p1[0]=f2bf(v2.x); p1[1]=f2bf(v2.y); p1[2]=f2bf(v2.z); p1[3]=f2bf(v2.w);
        p1[4]=f2bf(v3.x); p1[5]=f2bf(v3.y); p1[6]=f2bf(v3.z); p1[7]=f2bf(v3.w);
        *(u16x8*)&As[lr][lc]     = p0;
        *(u16x8*)&As[lr][lc + 8] = p1;
        // stage B (bf16 direct)
        const u16x8* wr = (const u16x8*)(w1e + (size_t)(n0 + lr) * D_ + k0 + lc);
        *(u16x8*)&Bs[lr][lc]     = wr[0];
        *(u16x8*)&Bs[lr][lc + 8] = wr[1];
        __syncthreads();
        #pragma unroll
        for (int kk = 0; kk < 64; kk += 32) {
            bf16x8 a0  = *(const bf16x8*)&As[wm + fm][kk + fk];
            bf16x8 a1  = *(const bf16x8*)&As[wm + 16 + fm][kk + fk];
            bf16x8 bb0 = *(const bf16x8*)&Bs[wn + fm][kk + fk];
            bf16x8 bb1 = *(const bf16x8*)&Bs[wn + 16 + fm][kk + fk];
            acc[0][0] = __builtin_amdgcn_mfma_f32_16x16x32_bf16(a0, bb0, acc[0][0], 0, 0, 0);
            acc[0][1] = __builtin_amdgcn_mfma_f32_16x16x32_bf16(a0, bb1, acc[0][1], 0, 0, 0);
            acc[1][0] = __builtin_amdgcn_mfma_f32_16x16x32_bf16(a1, bb0, acc[1][0], 0, 0, 0);
            acc[1][1] = __builtin_amdgcn_mfma_f32_16x16x32_bf16(a1, bb1, acc[1][1], 0, 0, 0);
        }
        __syncthreads();
    }

    const int orb  = (lane >> 4) * 4;
    const int ocol = lane & 15;
    #pragma unroll
    for (int i = 0; i < 2; ++i) {
        #pragma unroll
        for (int r = 0; r < 4; ++r) {
            int row = wm + i * 16 + orb + r;
            int m = m0 + row;
            if (m >= n_e) continue;
            ushort_t* hrow = hbuf + (size_t)(off + m) * H_;
            #pragma unroll
            for (int j = 0; j < 2; ++j) {
                int col = n0 + wn + j * 16 + ocol;
                float v = acc[i][j][r] + b1[e * H_ + col];
                hrow[col] = f2bf(gelu_exact(v));
            }
        }
    }
}

// ---------------------------------------------------------------------------
// Layer 2: per expert, hbuf [n_e,512] @ W2t[e] ([D][H] bf16), *gate, atomic +out
// grid: (128, D/64=16, E)
// ---------------------------------------------------------------------------
__global__ __launch_bounds__(256) void mlp2_kernel(
    const ushort_t* __restrict__ hbuf, const ushort_t* __restrict__ w2t,
    const float* __restrict__ b2,
    const int* __restrict__ counts, const int* __restrict__ offsets,
    const int* __restrict__ btok, const float* __restrict__ bgate,
    float* __restrict__ out)
{
    const int e   = blockIdx.z;
    const int n_e = counts[e];
    const int m0  = blockIdx.x * 64;
    if (m0 >= n_e) return;
    const int n0  = blockIdx.y * 64;
    const int off = offsets[e];

    __shared__ ushort_t As[64][72];
    __shared__ ushort_t Bs[64][72];

    const int tid = threadIdx.x;
    const int lr = tid >> 2;
    const int lc = (tid & 3) * 16;

    const int lane = tid & 63;
    const int wave = tid >> 6;
    const int wm = (wave & 1) * 32;
    const int wn = (wave >> 1) * 32;
    const int fm = lane & 15;
    const int fk = (lane >> 4) * 8;

    f32x4 acc[2][2];
    #pragma unroll
    for (int i = 0; i < 2; ++i)
        #pragma unroll
        for (int j = 0; j < 2; ++j)
            { acc[i][j][0]=0.f; acc[i][j][1]=0.f; acc[i][j][2]=0.f; acc[i][j][3]=0.f; }

    const ushort_t* arow = hbuf + (size_t)(off + m0 + lr) * H_;   // slack rows cover OOB
    const ushort_t* w2e  = w2t + (size_t)e * (D_ * H_);           // [D][H] bf16

    for (int k0 = 0; k0 < H_; k0 += 64) {
        *(u16x8*)&As[lr][lc]     = *(const u16x8*)(arow + k0 + lc);
        *(u16x8*)&As[lr][lc + 8] = *(const u16x8*)(arow + k0 + lc + 8);
        const u16x8* wr = (const u16x8*)(w2e + (size_t)(n0 + lr) * H_ + k0 + lc);
        *(u16x8*)&Bs[lr][lc]     = wr[0];
        *(u16x8*)&Bs[lr][lc + 8] = wr[1];
        __syncthreads();
        #pragma unroll
        for (int kk = 0; kk < 64; kk += 32) {
            bf16x8 a0  = *(const bf16x8*)&As[wm + fm][kk + fk];
            bf16x8 a1  = *(const bf16x8*)&As[wm + 16 + fm][kk + fk];
            bf16x8 bb0 = *(const bf16x8*)&Bs[wn + fm][kk + fk];
            bf16x8 bb1 = *(const bf16x8*)&Bs[wn + 16 + fm][kk + fk];
            acc[0][0] = __builtin_amdgcn_mfma_f32_16x16x32_bf16(a0, bb0, acc[0][0], 0, 0, 0);
            acc[0][1] = __builtin_amdgcn_mfma_f32_16x16x32_bf16(a0, bb1, acc[0][1], 0, 0, 0);
            acc[1][0] = __builtin_amdgcn_mfma_f32_16x16x32_bf16(a1, bb0, acc[1][0], 0, 0, 0);
            acc[1][1] = __builtin_amdgcn_mfma_f32_16x16x32_bf16(a1, bb1, acc[1][1], 0, 0, 0);
        }
        __syncthreads();
    }

    const int orb  = (lane >> 4) * 4;
    const int ocol = lane & 15;
    #pragma unroll
    for (int i = 0; i < 2; ++i) {
        #pragma unroll
        for (int r = 0; r < 4; ++r) {
            int row = wm + i * 16 + orb + r;
            int m = m0 + row;
            if (m >= n_e) continue;
            int tok = btok[e * T_ + m];
            float g = bgate[e * T_ + m];
            float* orow = out + (size_t)tok * D_;
            #pragma unroll
            for (int j = 0; j < 2; ++j) {
                int col = n0 + wn + j * 16 + ocol;
                float v = (acc[i][j][r] + b2[e * D_ + col]) * g;
                unsafeAtomicAdd(orow + col, v);   // native global_atomic_add_f32
            }
        }
    }
}

// ---------------------------------------------------------------------------
extern "C" void kernel_launch(void* const* d_in, const int* in_sizes, int n_in,
                              void* d_out, int out_size, void* d_ws, size_t ws_size,
                              hipStream_t stream)
{
    const float* x  = (const float*)d_in[0];
    const float* gw = (const float*)d_in[1];
    const float* gb = (const float*)d_in[2];
    const float* w1 = (const float*)d_in[3];
    const float* b1 = (const float*)d_in[4];
    const float* w2 = (const float*)d_in[5];
    const float* b2 = (const float*)d_in[6];
    float* out = (float*)d_out;

    // workspace layout (bytes)
    char* ws = (char*)d_ws;
    int*   counts  = (int*)ws;                                   // 8 ints
    int*   offsets = counts + 8;                                 // 8 ints
    int*   btok    = (int*)(ws + 256);                           // E*T ints   (1 MB)
    float* bgate   = (float*)(ws + 256 + (size_t)E_*T_*4);       // E*T floats
    size_t p = 256 + 2ull * E_ * T_ * 4;                         // 524544
    ushort_t* w1t  = (ushort_t*)(ws + p); p += (size_t)E_*H_*D_*2;   // bf16 [E][H][D]
    ushort_t* w2t  = (ushort_t*)(ws + p); p += (size_t)E_*D_*H_*2;   // bf16 [E][D][H]
    ushort_t* hbuf = (ushort_t*)(ws + p);                        // bf16 [2T+64][H]

    hipMemsetAsync(counts, 0, 64, stream);
    hipMemsetAsync(out, 0, (size_t)out_size * sizeof(float), stream);

    transpose_cvt<<<dim3(H_/32, D_/32, E_), 256, 0, stream>>>(w1, w1t, D_, H_);
    transpose_cvt<<<dim3(D_/32, H_/32, E_), 256, 0, stream>>>(w2, w2t, H_, D_);
    gating_kernel<<<T_, 64, 0, stream>>>(x, gw, gb, counts, btok, bgate);
    prefix_kernel<<<1, 64, 0, stream>>>(counts, offsets);
    mlp1_kernel<<<dim3(T_/64, H_/64, E_), 256, 0, stream>>>(
        x, w1t, b1, counts, offsets, btok, hbuf);
    mlp2_kernel<<<dim3(T_/64, D_/64, E_), 256, 0, stream>>>(
        hbuf, w2t, b2, counts, offsets, btok, bgate, out);
}

// Round 2
// 307.110 us; speedup vs baseline: 1.5091x; 1.5091x over previous
//
#include <hip/hip_runtime.h>
#include <hip/hip_bf16.h>

#define B_    4
#define L_    2048
#define T_    8192      // B*L tokens
#define D_    1024
#define E_    8
#define H_    512

typedef __bf16  bf16x8 __attribute__((ext_vector_type(8)));
typedef float   f32x4  __attribute__((ext_vector_type(4)));
typedef unsigned short u16x8 __attribute__((ext_vector_type(8)));
typedef unsigned short ushort_t;

__device__ __forceinline__ ushort_t f2bf(float f) {
    union { float f; unsigned u; } v; v.f = f;
    unsigned u = v.u;
    // round-to-nearest-even to bf16
    unsigned r = (u + 0x7fffu + ((u >> 16) & 1u)) >> 16;
    return (ushort_t)r;
}

__device__ __forceinline__ float gelu_exact(float v) {
    return 0.5f * v * (1.0f + erff(v * 0.70710678118654752f));
}

// ---------------------------------------------------------------------------
// Transpose + fp32->bf16 convert:  in [nmat][R][C] f32  ->  out [nmat][C][R] bf16
// grid: (C/32, R/32, nmat), block: 256
// ---------------------------------------------------------------------------
__global__ __launch_bounds__(256) void transpose_cvt(
    const float* __restrict__ in, ushort_t* __restrict__ out, int R, int C)
{
    __shared__ float tile[32][33];
    const size_t matoff = (size_t)blockIdx.z * R * C;
    const float* src = in + matoff;
    ushort_t* dst = out + matoff;
    const int r0 = blockIdx.y * 32, c0 = blockIdx.x * 32;
    const int tid = threadIdx.x;
    const int lr = tid >> 3;          // 0..31
    const int lc = (tid & 7) * 4;     // 0..28
    float4 v = *(const float4*)(src + (size_t)(r0 + lr) * C + c0 + lc);
    tile[lr][lc+0] = v.x; tile[lr][lc+1] = v.y;
    tile[lr][lc+2] = v.z; tile[lr][lc+3] = v.w;
    __syncthreads();
    ushort4 o;
    o.x = f2bf(tile[lc+0][lr]);
    o.y = f2bf(tile[lc+1][lr]);
    o.z = f2bf(tile[lc+2][lr]);
    o.w = f2bf(tile[lc+3][lr]);
    *(ushort4*)(dst + (size_t)(c0 + lr) * R + r0 + lc) = o;
}

// ---------------------------------------------------------------------------
// Gating phase 1: fp32 logits, top-2 select. One wave per token, 4 tokens/block.
// NO atomics — writes packed expert pair + top gate per token.
// ---------------------------------------------------------------------------
__global__ __launch_bounds__(256) void gating_kernel(
    const float* __restrict__ x, const float* __restrict__ gw,
    const float* __restrict__ gb,
    int* __restrict__ eidx, float* __restrict__ gsel)
{
    const int wave = threadIdx.x >> 6;
    const int lane = threadIdx.x & 63;
    const int t = blockIdx.x * 4 + wave;
    const float* xr = x + (size_t)t * D_;

    float acc[E_];
    #pragma unroll
    for (int e = 0; e < E_; ++e) acc[e] = 0.f;

    #pragma unroll
    for (int j = 0; j < 4; ++j) {
        const int d = j * 256 + lane * 4;
        float4 xv = *(const float4*)(xr + d);
        const float* gr = gw + (size_t)d * E_;
        float xs[4] = {xv.x, xv.y, xv.z, xv.w};
        #pragma unroll
        for (int c = 0; c < 4; ++c) {
            float4 g0 = *(const float4*)(gr + c * 8);
            float4 g1 = *(const float4*)(gr + c * 8 + 4);
            acc[0] += xs[c] * g0.x; acc[1] += xs[c] * g0.y;
            acc[2] += xs[c] * g0.z; acc[3] += xs[c] * g0.w;
            acc[4] += xs[c] * g1.x; acc[5] += xs[c] * g1.y;
            acc[6] += xs[c] * g1.z; acc[7] += xs[c] * g1.w;
        }
    }
    #pragma unroll
    for (int s = 1; s < 64; s <<= 1) {
        #pragma unroll
        for (int e = 0; e < E_; ++e)
            acc[e] += __shfl_xor(acc[e], s, 64);
    }
    if (lane == 0) {
        float v[E_];
        #pragma unroll
        for (int e = 0; e < E_; ++e) v[e] = acc[e] + gb[e];
        int i0 = 0;
        #pragma unroll
        for (int e = 1; e < E_; ++e) if (v[e] > v[i0]) i0 = e;   // ties -> lowest idx
        int i1 = (i0 == 0) ? 1 : 0;
        #pragma unroll
        for (int e = 0; e < E_; ++e) if (e != i0 && v[e] > v[i1]) i1 = e;
        float g0 = 1.f / (1.f + expf(v[i1] - v[i0]));  // softmax over top-2
        eidx[t] = i0 | (i1 << 8);
        gsel[t] = g0;
    }
}

// ---------------------------------------------------------------------------
// Gating phase 2: bucketize. 256 tokens/block, LDS histogram + local offsets,
// then ONE global atomic per expert per block (8 x 32 = 256 total vs 16384).
// ---------------------------------------------------------------------------
__global__ __launch_bounds__(256) void bucket_kernel(
    const int* __restrict__ eidx, const float* __restrict__ gsel,
    int* __restrict__ counts, int* __restrict__ btok, float* __restrict__ bgate)
{
    __shared__ int lcnt[E_];
    __shared__ int lbase[E_];
    const int tid = threadIdx.x;
    if (tid < E_) lcnt[tid] = 0;
    __syncthreads();
    const int t = blockIdx.x * 256 + tid;
    const int pk = eidx[t];
    const float g0 = gsel[t];
    const int i0 = pk & 0xff, i1 = (pk >> 8) & 0xff;
    const int p0 = atomicAdd(&lcnt[i0], 1);
    const int p1 = atomicAdd(&lcnt[i1], 1);
    __syncthreads();
    if (tid < E_) lbase[tid] = atomicAdd(&counts[tid], lcnt[tid]);
    __syncthreads();
    const int q0 = lbase[i0] + p0, q1 = lbase[i1] + p1;
    btok[i0 * T_ + q0] = t; bgate[i0 * T_ + q0] = g0;
    btok[i1 * T_ + q1] = t; bgate[i1 * T_ + q1] = 1.f - g0;
}

__global__ void prefix_kernel(const int* __restrict__ counts, int* __restrict__ offsets)
{
    if (threadIdx.x == 0 && blockIdx.x == 0) {
        int s = 0;
        for (int e = 0; e < E_; ++e) { offsets[e] = s; s += counts[e]; }
    }
}

// ---------------------------------------------------------------------------
// Layer 1: per expert, gathered X [n_e,1024] @ W1t[e] -> gelu -> hbuf bf16
// tiles 64x64x64, 256 thr = 4 waves, wave computes 32x32 (2x2 16x16x32 MFMA)
// grid: (128, H/64=8, E)
// ---------------------------------------------------------------------------
__global__ __launch_bounds__(256) void mlp1_kernel(
    const float* __restrict__ x, const ushort_t* __restrict__ w1t,
    const float* __restrict__ b1,
    const int* __restrict__ counts, const int* __restrict__ offsets,
    const int* __restrict__ btok, ushort_t* __restrict__ hbuf)
{
    const int e   = blockIdx.z;
    const int n_e = counts[e];
    const int m0  = blockIdx.x * 64;
    if (m0 >= n_e) return;
    const int n0  = blockIdx.y * 64;
    const int off = offsets[e];

    __shared__ ushort_t As[64][72];   // +8 pad: 2-way bank alias only (free)
    __shared__ ushort_t Bs[64][72];
    __shared__ int toks[64];

    const int tid = threadIdx.x;
    if (tid < 64) {
        int m = m0 + tid;
        toks[tid] = btok[e * T_ + (m < n_e ? m : n_e - 1)];
    }
    __syncthreads();

    const ushort_t* w1e = w1t + (size_t)e * (H_ * D_);   // [H][D] bf16

    const int lr = tid >> 2;          // staging row 0..63
    const int lc = (tid & 3) * 16;    // staging col group

    const int lane = tid & 63;
    const int wave = tid >> 6;
    const int wm = (wave & 1) * 32;
    const int wn = (wave >> 1) * 32;
    const int fm = lane & 15;
    const int fk = (lane >> 4) * 8;

    f32x4 acc[2][2];
    #pragma unroll
    for (int i = 0; i < 2; ++i)
        #pragma unroll
        for (int j = 0; j < 2; ++j)
            { acc[i][j][0]=0.f; acc[i][j][1]=0.f; acc[i][j][2]=0.f; acc[i][j][3]=0.f; }

    const float* xrow = x + (size_t)toks[lr] * D_;

    for (int k0 = 0; k0 < D_; k0 += 64) {
        // stage A (gather + fp32->bf16)
        float4 v0 = *(const float4*)(xrow + k0 + lc);
        float4 v1 = *(const float4*)(xrow + k0 + lc + 4);
        float4 v2 = *(const float4*)(xrow + k0 + lc + 8);
        float4 v3 = *(const float4*)(xrow + k0 + lc + 12);
        u16x8 p0, p1;
        p0[0]=f2bf(v0.x); p0[1]=f2bf(v0.y); p0[2]=f2bf(v0.z); p0[3]=f2bf(v0.w);
        p0[4]=f2bf(v1.x); p0[5]=f2bf(v1.y); p0[6]=f2bf(v1.z); p0[7]=f2bf(v1.w);
        p1[0]=f2bf(v2.x); p1[1]=f2bf(v2.y); p1[2]=f2bf(v2.z); p1[3]=f2bf(v2.w);
        p1[4]=f2bf(v3.x); p1[5]=f2bf(v3.y); p1[6]=f2bf(v3.z); p1[7]=f2bf(v3.w);
        *(u16x8*)&As[lr][lc]     = p0;
        *(u16x8*)&As[lr][lc + 8] = p1;
        // stage B (bf16 direct)
        const u16x8* wr = (const u16x8*)(w1e + (size_t)(n0 + lr) * D_ + k0 + lc);
        *(u16x8*)&Bs[lr][lc]     = wr[0];
        *(u16x8*)&Bs[lr][lc + 8] = wr[1];
        __syncthreads();
        #pragma unroll
        for (int kk = 0; kk < 64; kk += 32) {
            bf16x8 a0  = *(const bf16x8*)&As[wm + fm][kk + fk];
            bf16x8 a1  = *(const bf16x8*)&As[wm + 16 + fm][kk + fk];
            bf16x8 bb0 = *(const bf16x8*)&Bs[wn + fm][kk + fk];
            bf16x8 bb1 = *(const bf16x8*)&Bs[wn + 16 + fm][kk + fk];
            acc[0][0] = __builtin_amdgcn_mfma_f32_16x16x32_bf16(a0, bb0, acc[0][0], 0, 0, 0);
            acc[0][1] = __builtin_amdgcn_mfma_f32_16x16x32_bf16(a0, bb1, acc[0][1], 0, 0, 0);
            acc[1][0] = __builtin_amdgcn_mfma_f32_16x16x32_bf16(a1, bb0, acc[1][0], 0, 0, 0);
            acc[1][1] = __builtin_amdgcn_mfma_f32_16x16x32_bf16(a1, bb1, acc[1][1], 0, 0, 0);
        }
        __syncthreads();
    }

    const int orb  = (lane >> 4) * 4;
    const int ocol = lane & 15;
    #pragma unroll
    for (int i = 0; i < 2; ++i) {
        #pragma unroll
        for (int r = 0; r < 4; ++r) {
            int row = wm + i * 16 + orb + r;
            int m = m0 + row;
            if (m >= n_e) continue;
            ushort_t* hrow = hbuf + (size_t)(off + m) * H_;
            #pragma unroll
            for (int j = 0; j < 2; ++j) {
                int col = n0 + wn + j * 16 + ocol;
                float v = acc[i][j][r] + b1[e * H_ + col];
                hrow[col] = f2bf(gelu_exact(v));
            }
        }
    }
}

// ---------------------------------------------------------------------------
// Layer 2: per expert, hbuf [n_e,512] @ W2t[e] ([D][H] bf16), *gate, atomic +out
// grid: (128, D/64=16, E)
// ---------------------------------------------------------------------------
__global__ __launch_bounds__(256) void mlp2_kernel(
    const ushort_t* __restrict__ hbuf, const ushort_t* __restrict__ w2t,
    const float* __restrict__ b2,
    const int* __restrict__ counts, const int* __restrict__ offsets,
    const int* __restrict__ btok, const float* __restrict__ bgate,
    float* __restrict__ out)
{
    const int e   = blockIdx.z;
    const int n_e = counts[e];
    const int m0  = blockIdx.x * 64;
    if (m0 >= n_e) return;
    const int n0  = blockIdx.y * 64;
    const int off = offsets[e];

    __shared__ ushort_t As[64][72];
    __shared__ ushort_t Bs[64][72];

    const int tid = threadIdx.x;
    const int lr = tid >> 2;
    const int lc = (tid & 3) * 16;

    const int lane = tid & 63;
    const int wave = tid >> 6;
    const int wm = (wave & 1) * 32;
    const int wn = (wave >> 1) * 32;
    const int fm = lane & 15;
    const int fk = (lane >> 4) * 8;

    f32x4 acc[2][2];
    #pragma unroll
    for (int i = 0; i < 2; ++i)
        #pragma unroll
        for (int j = 0; j < 2; ++j)
            { acc[i][j][0]=0.f; acc[i][j][1]=0.f; acc[i][j][2]=0.f; acc[i][j][3]=0.f; }

    const ushort_t* arow = hbuf + (size_t)(off + m0 + lr) * H_;   // slack rows cover OOB
    const ushort_t* w2e  = w2t + (size_t)e * (D_ * H_);           // [D][H] bf16

    for (int k0 = 0; k0 < H_; k0 += 64) {
        *(u16x8*)&As[lr][lc]     = *(const u16x8*)(arow + k0 + lc);
        *(u16x8*)&As[lr][lc + 8] = *(const u16x8*)(arow + k0 + lc + 8);
        const u16x8* wr = (const u16x8*)(w2e + (size_t)(n0 + lr) * H_ + k0 + lc);
        *(u16x8*)&Bs[lr][lc]     = wr[0];
        *(u16x8*)&Bs[lr][lc + 8] = wr[1];
        __syncthreads();
        #pragma unroll
        for (int kk = 0; kk < 64; kk += 32) {
            bf16x8 a0  = *(const bf16x8*)&As[wm + fm][kk + fk];
            bf16x8 a1  = *(const bf16x8*)&As[wm + 16 + fm][kk + fk];
            bf16x8 bb0 = *(const bf16x8*)&Bs[wn + fm][kk + fk];
            bf16x8 bb1 = *(const bf16x8*)&Bs[wn + 16 + fm][kk + fk];
            acc[0][0] = __builtin_amdgcn_mfma_f32_16x16x32_bf16(a0, bb0, acc[0][0], 0, 0, 0);
            acc[0][1] = __builtin_amdgcn_mfma_f32_16x16x32_bf16(a0, bb1, acc[0][1], 0, 0, 0);
            acc[1][0] = __builtin_amdgcn_mfma_f32_16x16x32_bf16(a1, bb0, acc[1][0], 0, 0, 0);
            acc[1][1] = __builtin_amdgcn_mfma_f32_16x16x32_bf16(a1, bb1, acc[1][1], 0, 0, 0);
        }
        __syncthreads();
    }

    const int orb  = (lane >> 4) * 4;
    const int ocol = lane & 15;
    #pragma unroll
    for (int i = 0; i < 2; ++i) {
        #pragma unroll
        for (int r = 0; r < 4; ++r) {
            int row = wm + i * 16 + orb + r;
            int m = m0 + row;
            if (m >= n_e) continue;
            int tok = btok[e * T_ + m];
            float g = bgate[e * T_ + m];
            float* orow = out + (size_t)tok * D_;
            #pragma unroll
            for (int j = 0; j < 2; ++j) {
                int col = n0 + wn + j * 16 + ocol;
                float v = (acc[i][j][r] + b2[e * D_ + col]) * g;
                unsafeAtomicAdd(orow + col, v);   // native global_atomic_add_f32
            }
        }
    }
}

// ---------------------------------------------------------------------------
extern "C" void kernel_launch(void* const* d_in, const int* in_sizes, int n_in,
                              void* d_out, int out_size, void* d_ws, size_t ws_size,
                              hipStream_t stream)
{
    const float* x  = (const float*)d_in[0];
    const float* gw = (const float*)d_in[1];
    const float* gb = (const float*)d_in[2];
    const float* w1 = (const float*)d_in[3];
    const float* b1 = (const float*)d_in[4];
    const float* w2 = (const float*)d_in[5];
    const float* b2 = (const float*)d_in[6];
    float* out = (float*)d_out;

    // workspace layout (bytes)
    char* ws = (char*)d_ws;
    int*   counts  = (int*)ws;                                   // 8 ints
    int*   offsets = counts + 8;                                 // 8 ints
    int*   btok    = (int*)(ws + 256);                           // E*T ints   (1 MB)
    float* bgate   = (float*)(ws + 256 + (size_t)E_*T_*4);       // E*T floats
    size_t p = 256 + 2ull * E_ * T_ * 4;                         // 524544
    int*   eidx    = (int*)(ws + p); p += (size_t)T_ * 4;        // packed top-2 idx
    float* gsel    = (float*)(ws + p); p += (size_t)T_ * 4;      // top gate
    ushort_t* w1t  = (ushort_t*)(ws + p); p += (size_t)E_*H_*D_*2;   // bf16 [E][H][D]
    ushort_t* w2t  = (ushort_t*)(ws + p); p += (size_t)E_*D_*H_*2;   // bf16 [E][D][H]
    ushort_t* hbuf = (ushort_t*)(ws + p);                        // bf16 [2T+64][H]

    hipMemsetAsync(counts, 0, 64, stream);
    hipMemsetAsync(out, 0, (size_t)out_size * sizeof(float), stream);

    transpose_cvt<<<dim3(H_/32, D_/32, E_), 256, 0, stream>>>(w1, w1t, D_, H_);
    transpose_cvt<<<dim3(D_/32, H_/32, E_), 256, 0, stream>>>(w2, w2t, H_, D_);
    gating_kernel<<<T_/4, 256, 0, stream>>>(x, gw, gb, eidx, gsel);
    bucket_kernel<<<T_/256, 256, 0, stream>>>(eidx, gsel, counts, btok, bgate);
    prefix_kernel<<<1, 64, 0, stream>>>(counts, offsets);
    mlp1_kernel<<<dim3(T_/64, H_/64, E_), 256, 0, stream>>>(
        x, w1t, b1, counts, offsets, btok, hbuf);
    mlp2_kernel<<<dim3(T_/64, D_/64, E_), 256, 0, stream>>>(
        hbuf, w2t, b2, counts, offsets, btok, bgate, out);
}

// Round 4
// 298.531 us; speedup vs baseline: 1.5525x; 1.0287x over previous
//
#include <hip/hip_runtime.h>
#include <hip/hip_bf16.h>
#include <stdint.h>

#define B_    4
#define L_    2048
#define T_    8192      // B*L tokens
#define D_    1024
#define E_    8
#define H_    512

typedef __bf16  bf16x8 __attribute__((ext_vector_type(8)));
typedef float   f32x4  __attribute__((ext_vector_type(4)));
typedef unsigned short ushort_t;

__device__ __forceinline__ ushort_t f2bf(float f) {
    union { float f; unsigned u; } v; v.f = f;
    unsigned u = v.u;
    unsigned r = (u + 0x7fffu + ((u >> 16) & 1u)) >> 16;   // RNE
    return (ushort_t)r;
}

__device__ __forceinline__ float gelu_exact(float v) {
    return 0.5f * v * (1.0f + erff(v * 0.70710678118654752f));
}

// async global->LDS, 16B per lane; LDS dest = wave-uniform base + lane*16
__device__ __forceinline__ void gld_lds16(const void* g, void* l) {
    __attribute__((address_space(3))) uint32_t* lp =
        reinterpret_cast<__attribute__((address_space(3))) uint32_t*>(
            reinterpret_cast<uintptr_t>(l));
    const __attribute__((address_space(1))) uint32_t* gp =
        reinterpret_cast<const __attribute__((address_space(1))) uint32_t*>(
            reinterpret_cast<uintptr_t>(g));
    __builtin_amdgcn_global_load_lds(gp, lp, 16, 0, 0);
}

// ---------------------------------------------------------------------------
// Transpose + fp32->bf16:  in [nmat][R][C] f32 -> out [nmat][C][R] bf16
// ---------------------------------------------------------------------------
__global__ __launch_bounds__(256) void transpose_cvt(
    const float* __restrict__ in, ushort_t* __restrict__ out, int R, int C)
{
    __shared__ float tile[32][33];
    const size_t matoff = (size_t)blockIdx.z * R * C;
    const float* src = in + matoff;
    ushort_t* dst = out + matoff;
    const int r0 = blockIdx.y * 32, c0 = blockIdx.x * 32;
    const int tid = threadIdx.x;
    const int lr = tid >> 3;
    const int lc = (tid & 7) * 4;
    float4 v = *(const float4*)(src + (size_t)(r0 + lr) * C + c0 + lc);
    tile[lr][lc+0] = v.x; tile[lr][lc+1] = v.y;
    tile[lr][lc+2] = v.z; tile[lr][lc+3] = v.w;
    __syncthreads();
    ushort4 o;
    o.x = f2bf(tile[lc+0][lr]);
    o.y = f2bf(tile[lc+1][lr]);
    o.z = f2bf(tile[lc+2][lr]);
    o.w = f2bf(tile[lc+3][lr]);
    *(ushort4*)(dst + (size_t)(c0 + lr) * R + r0 + lc) = o;
}

// ---------------------------------------------------------------------------
// Gating phase 1 + x fp32->bf16 conversion (x is fully read here anyway).
// One wave per token, 4 tokens/block. No atomics.
// ---------------------------------------------------------------------------
__global__ __launch_bounds__(256) void gating_kernel(
    const float* __restrict__ x, const float* __restrict__ gw,
    const float* __restrict__ gb,
    int* __restrict__ eidx, float* __restrict__ gsel, ushort_t* __restrict__ xbf)
{
    const int wave = threadIdx.x >> 6;
    const int lane = threadIdx.x & 63;
    const int t = blockIdx.x * 4 + wave;
    const float* xr = x + (size_t)t * D_;
    ushort_t* xbr = xbf + (size_t)t * D_;

    float acc[E_];
    #pragma unroll
    for (int e = 0; e < E_; ++e) acc[e] = 0.f;

    #pragma unroll
    for (int j = 0; j < 4; ++j) {
        const int d = j * 256 + lane * 4;
        float4 xv = *(const float4*)(xr + d);
        ushort4 o;
        o.x = f2bf(xv.x); o.y = f2bf(xv.y); o.z = f2bf(xv.z); o.w = f2bf(xv.w);
        *(ushort4*)(xbr + d) = o;
        const float* gr = gw + (size_t)d * E_;
        float xs[4] = {xv.x, xv.y, xv.z, xv.w};
        #pragma unroll
        for (int c = 0; c < 4; ++c) {
            float4 g0 = *(const float4*)(gr + c * 8);
            float4 g1 = *(const float4*)(gr + c * 8 + 4);
            acc[0] += xs[c] * g0.x; acc[1] += xs[c] * g0.y;
            acc[2] += xs[c] * g0.z; acc[3] += xs[c] * g0.w;
            acc[4] += xs[c] * g1.x; acc[5] += xs[c] * g1.y;
            acc[6] += xs[c] * g1.z; acc[7] += xs[c] * g1.w;
        }
    }
    #pragma unroll
    for (int s = 1; s < 64; s <<= 1) {
        #pragma unroll
        for (int e = 0; e < E_; ++e)
            acc[e] += __shfl_xor(acc[e], s, 64);
    }
    if (lane == 0) {
        float v[E_];
        #pragma unroll
        for (int e = 0; e < E_; ++e) v[e] = acc[e] + gb[e];
        int i0 = 0;
        #pragma unroll
        for (int e = 1; e < E_; ++e) if (v[e] > v[i0]) i0 = e;
        int i1 = (i0 == 0) ? 1 : 0;
        #pragma unroll
        for (int e = 0; e < E_; ++e) if (e != i0 && v[e] > v[i1]) i1 = e;
        float g0 = 1.f / (1.f + expf(v[i1] - v[i0]));
        eidx[t] = i0 | (i1 << 8);
        gsel[t] = g0;
    }
}

// ---------------------------------------------------------------------------
// Gating phase 2: bucketize, 8 global atomics per 256-token block.
// ---------------------------------------------------------------------------
__global__ __launch_bounds__(256) void bucket_kernel(
    const int* __restrict__ eidx, const float* __restrict__ gsel,
    int* __restrict__ counts, int* __restrict__ btok, float* __restrict__ bgate)
{
    __shared__ int lcnt[E_];
    __shared__ int lbase[E_];
    const int tid = threadIdx.x;
    if (tid < E_) lcnt[tid] = 0;
    __syncthreads();
    const int t = blockIdx.x * 256 + tid;
    const int pk = eidx[t];
    const float g0 = gsel[t];
    const int i0 = pk & 0xff, i1 = (pk >> 8) & 0xff;
    const int p0 = atomicAdd(&lcnt[i0], 1);
    const int p1 = atomicAdd(&lcnt[i1], 1);
    __syncthreads();
    if (tid < E_) lbase[tid] = atomicAdd(&counts[tid], lcnt[tid]);
    __syncthreads();
    const int q0 = lbase[i0] + p0, q1 = lbase[i1] + p1;
    btok[i0 * T_ + q0] = t; bgate[i0 * T_ + q0] = g0;
    btok[i1 * T_ + q1] = t; bgate[i1 * T_ + q1] = 1.f - g0;
}

__global__ void prefix_kernel(const int* __restrict__ counts, int* __restrict__ offsets)
{
    if (threadIdx.x == 0 && blockIdx.x == 0) {
        int s = 0;
        for (int e = 0; e < E_; ++e) { offsets[e] = s; s += counts[e]; }
    }
}

// ---------------------------------------------------------------------------
// Shared GEMM tile machinery: 128x128 tile, BK=64, 4 waves, 4x4 16x16x32 MFMA
// LDS [128 rows][64 cols] bf16, XOR-swizzled col groups (grp ^= row&7).
// Staged via global_load_lds (wave-uniform base + lane*16).
// ---------------------------------------------------------------------------

// Layer 1: gathered xbf [n_e,1024] @ W1t[e] ([H][D]) -> gelu -> hbuf bf16
// grid: (64, H/128=4, E)
__global__ __launch_bounds__(256) void mlp1_kernel(
    const ushort_t* __restrict__ xbf, const ushort_t* __restrict__ w1t,
    const float* __restrict__ b1,
    const int* __restrict__ counts, const int* __restrict__ offsets,
    const int* __restrict__ btok, ushort_t* __restrict__ hbuf)
{
    const int e   = blockIdx.z;
    const int n_e = counts[e];
    const int m0  = blockIdx.x * 128;
    if (m0 >= n_e) return;
    const int n0  = blockIdx.y * 128;
    const int off = offsets[e];

    __shared__ ushort_t As[128 * 64];
    __shared__ ushort_t Bs[128 * 64];

    const int tid  = threadIdx.x;
    const int lane = tid & 63;
    const int wave = tid >> 6;

    // staging geometry: instr i covers rows i*32 + tid/8, col group (tid&7)^swz
    const int srow = tid >> 3;                    // 0..31
    const int cg   = (tid & 7) ^ (srow & 7);      // swizzled global col group

    const ushort_t* aptr[4];
    #pragma unroll
    for (int i = 0; i < 4; ++i) {
        int m = m0 + i * 32 + srow;
        int tok = btok[e * T_ + (m < n_e ? m : n_e - 1)];
        aptr[i] = xbf + (size_t)tok * D_ + cg * 8;
    }
    const ushort_t* w1e = w1t + (size_t)e * (H_ * D_);
    const ushort_t* bptr[4];
    #pragma unroll
    for (int i = 0; i < 4; ++i)
        bptr[i] = w1e + (size_t)(n0 + i * 32 + srow) * D_ + cg * 8;

    char* aldst = (char*)As + (wave << 10);
    char* bldst = (char*)Bs + (wave << 10);

    const int fm   = lane & 15;
    const int quad = lane >> 4;
    const int wm   = (wave & 1) * 64;
    const int wn   = (wave >> 1) * 64;

    f32x4 acc[4][4];
    #pragma unroll
    for (int i = 0; i < 4; ++i)
        #pragma unroll
        for (int j = 0; j < 4; ++j)
            { acc[i][j][0]=0.f; acc[i][j][1]=0.f; acc[i][j][2]=0.f; acc[i][j][3]=0.f; }

    for (int k0 = 0; k0 < D_; k0 += 64) {
        #pragma unroll
        for (int i = 0; i < 4; ++i)
            gld_lds16(aptr[i] + k0, aldst + (i << 12));
        #pragma unroll
        for (int i = 0; i < 4; ++i)
            gld_lds16(bptr[i] + k0, bldst + (i << 12));
        __syncthreads();
        #pragma unroll
        for (int kk = 0; kk < 2; ++kk) {
            const int grp = kk * 4 + quad;
            bf16x8 af[4], bfr[4];
            #pragma unroll
            for (int i = 0; i < 4; ++i) {
                int ra = wm + i * 16 + fm;
                af[i]  = *(const bf16x8*)((const char*)As + ra * 128 + ((grp ^ (ra & 7)) << 4));
                int rb = wn + i * 16 + fm;
                bfr[i] = *(const bf16x8*)((const char*)Bs + rb * 128 + ((grp ^ (rb & 7)) << 4));
            }
            #pragma unroll
            for (int i = 0; i < 4; ++i)
                #pragma unroll
                for (int j = 0; j < 4; ++j)
                    acc[i][j] = __builtin_amdgcn_mfma_f32_16x16x32_bf16(af[i], bfr[j], acc[i][j], 0, 0, 0);
        }
        __syncthreads();
    }

    // epilogue: C row = quad*4+reg, col = fm
    float bcol[4];
    #pragma unroll
    for (int j = 0; j < 4; ++j)
        bcol[j] = b1[e * H_ + n0 + wn + j * 16 + fm];
    #pragma unroll
    for (int i = 0; i < 4; ++i) {
        #pragma unroll
        for (int r = 0; r < 4; ++r) {
            int m = m0 + wm + i * 16 + quad * 4 + r;
            if (m >= n_e) continue;
            ushort_t* hrow = hbuf + (size_t)(off + m) * H_ + n0;
            #pragma unroll
            for (int j = 0; j < 4; ++j)
                hrow[wn + j * 16 + fm] = f2bf(gelu_exact(acc[i][j][r] + bcol[j]));
        }
    }
}

// Layer 2: hbuf [n_e,512] @ W2t[e] ([D][H]) -> *gate + bias -> atomic out
// grid: (64, D/128=8, E)
__global__ __launch_bounds__(256) void mlp2_kernel(
    const ushort_t* __restrict__ hbuf, const ushort_t* __restrict__ w2t,
    const float* __restrict__ b2,
    const int* __restrict__ counts, const int* __restrict__ offsets,
    const int* __restrict__ btok, const float* __restrict__ bgate,
    float* __restrict__ out)
{
    const int e   = blockIdx.z;
    const int n_e = counts[e];
    const int m0  = blockIdx.x * 128;
    if (m0 >= n_e) return;
    const int n0  = blockIdx.y * 128;
    const int off = offsets[e];

    __shared__ ushort_t As[128 * 64];
    __shared__ ushort_t Bs[128 * 64];

    const int tid  = threadIdx.x;
    const int lane = tid & 63;
    const int wave = tid >> 6;

    const int srow = tid >> 3;
    const int cg   = (tid & 7) ^ (srow & 7);

    const ushort_t* aptr[4];
    #pragma unroll
    for (int i = 0; i < 4; ++i)
        aptr[i] = hbuf + (size_t)(off + m0 + i * 32 + srow) * H_ + cg * 8;  // slack rows ok
    const ushort_t* w2e = w2t + (size_t)e * (D_ * H_);
    const ushort_t* bptr[4];
    #pragma unroll
    for (int i = 0; i < 4; ++i)
        bptr[i] = w2e + (size_t)(n0 + i * 32 + srow) * H_ + cg * 8;

    char* aldst = (char*)As + (wave << 10);
    char* bldst = (char*)Bs + (wave << 10);

    const int fm   = lane & 15;
    const int quad = lane >> 4;
    const int wm   = (wave & 1) * 64;
    const int wn   = (wave >> 1) * 64;

    f32x4 acc[4][4];
    #pragma unroll
    for (int i = 0; i < 4; ++i)
        #pragma unroll
        for (int j = 0; j < 4; ++j)
            { acc[i][j][0]=0.f; acc[i][j][1]=0.f; acc[i][j][2]=0.f; acc[i][j][3]=0.f; }

    for (int k0 = 0; k0 < H_; k0 += 64) {
        #pragma unroll
        for (int i = 0; i < 4; ++i)
            gld_lds16(aptr[i] + k0, aldst + (i << 12));
        #pragma unroll
        for (int i = 0; i < 4; ++i)
            gld_lds16(bptr[i] + k0, bldst + (i << 12));
        __syncthreads();
        #pragma unroll
        for (int kk = 0; kk < 2; ++kk) {
            const int grp = kk * 4 + quad;
            bf16x8 af[4], bfr[4];
            #pragma unroll
            for (int i = 0; i < 4; ++i) {
                int ra = wm + i * 16 + fm;
                af[i]  = *(const bf16x8*)((const char*)As + ra * 128 + ((grp ^ (ra & 7)) << 4));
                int rb = wn + i * 16 + fm;
                bfr[i] = *(const bf16x8*)((const char*)Bs + rb * 128 + ((grp ^ (rb & 7)) << 4));
            }
            #pragma unroll
            for (int i = 0; i < 4; ++i)
                #pragma unroll
                for (int j = 0; j < 4; ++j)
                    acc[i][j] = __builtin_amdgcn_mfma_f32_16x16x32_bf16(af[i], bfr[j], acc[i][j], 0, 0, 0);
        }
        __syncthreads();
    }

    float bcol[4];
    #pragma unroll
    for (int j = 0; j < 4; ++j)
        bcol[j] = b2[e * D_ + n0 + wn + j * 16 + fm];
    #pragma unroll
    for (int i = 0; i < 4; ++i) {
        #pragma unroll
        for (int r = 0; r < 4; ++r) {
            int m = m0 + wm + i * 16 + quad * 4 + r;
            if (m >= n_e) continue;
            int   tok = btok[e * T_ + m];
            float g   = bgate[e * T_ + m];
            float* orow = out + (size_t)tok * D_ + n0;
            #pragma unroll
            for (int j = 0; j < 4; ++j) {
                float v = (acc[i][j][r] + bcol[j]) * g;
                unsafeAtomicAdd(orow + wn + j * 16 + fm, v);
            }
        }
    }
}

// ---------------------------------------------------------------------------
extern "C" void kernel_launch(void* const* d_in, const int* in_sizes, int n_in,
                              void* d_out, int out_size, void* d_ws, size_t ws_size,
                              hipStream_t stream)
{
    const float* x  = (const float*)d_in[0];
    const float* gw = (const float*)d_in[1];
    const float* gb = (const float*)d_in[2];
    const float* w1 = (const float*)d_in[3];
    const float* b1 = (const float*)d_in[4];
    const float* w2 = (const float*)d_in[5];
    const float* b2 = (const float*)d_in[6];
    float* out = (float*)d_out;

    // workspace layout
    char* ws = (char*)d_ws;
    int*   counts  = (int*)ws;                                   // 8 ints
    int*   offsets = counts + 8;
    int*   btok    = (int*)(ws + 256);                           // E*T ints
    float* bgate   = (float*)(ws + 256 + (size_t)E_*T_*4);
    size_t p = 256 + 2ull * E_ * T_ * 4;
    int*   eidx    = (int*)(ws + p); p += (size_t)T_ * 4;
    float* gsel    = (float*)(ws + p); p += (size_t)T_ * 4;
    ushort_t* xbf  = (ushort_t*)(ws + p); p += (size_t)T_*D_*2;      // bf16 x
    ushort_t* w1t  = (ushort_t*)(ws + p); p += (size_t)E_*H_*D_*2;   // bf16 [E][H][D]
    ushort_t* w2t  = (ushort_t*)(ws + p); p += (size_t)E_*D_*H_*2;   // bf16 [E][D][H]
    ushort_t* hbuf = (ushort_t*)(ws + p);                        // bf16 [2T+128][H]

    (void)hipMemsetAsync(counts, 0, 64, stream);
    (void)hipMemsetAsync(out, 0, (size_t)out_size * sizeof(float), stream);

    transpose_cvt<<<dim3(H_/32, D_/32, E_), 256, 0, stream>>>(w1, w1t, D_, H_);
    transpose_cvt<<<dim3(D_/32, H_/32, E_), 256, 0, stream>>>(w2, w2t, H_, D_);
    gating_kernel<<<T_/4, 256, 0, stream>>>(x, gw, gb, eidx, gsel, xbf);
    bucket_kernel<<<T_/256, 256, 0, stream>>>(eidx, gsel, counts, btok, bgate);
    prefix_kernel<<<1, 64, 0, stream>>>(counts, offsets);
    mlp1_kernel<<<dim3(T_/128, H_/128, E_), 256, 0, stream>>>(
        xbf, w1t, b1, counts, offsets, btok, hbuf);
    mlp2_kernel<<<dim3(T_/128, D_/128, E_), 256, 0, stream>>>(
        hbuf, w2t, b2, counts, offsets, btok, bgate, out);
}

// Round 5
// 268.074 us; speedup vs baseline: 1.7289x; 1.1136x over previous
//
#include <hip/hip_runtime.h>
#include <hip/hip_bf16.h>
#include <stdint.h>

#define B_    4
#define L_    2048
#define T_    8192      // B*L tokens
#define D_    1024
#define E_    8
#define H_    512

typedef __bf16  bf16x8 __attribute__((ext_vector_type(8)));
typedef float   f32x4  __attribute__((ext_vector_type(4)));
typedef unsigned short ushort_t;

__device__ __forceinline__ ushort_t f2bf(float f) {
    union { float f; unsigned u; } v; v.f = f;
    unsigned u = v.u;
    unsigned r = (u + 0x7fffu + ((u >> 16) & 1u)) >> 16;   // RNE
    return (ushort_t)r;
}

__device__ __forceinline__ float gelu_exact(float v) {
    return 0.5f * v * (1.0f + erff(v * 0.70710678118654752f));
}

// async global->LDS, 16B per lane; LDS dest = wave-uniform base + lane*16
__device__ __forceinline__ void gld_lds16(const void* g, void* l) {
    __attribute__((address_space(3))) uint32_t* lp =
        reinterpret_cast<__attribute__((address_space(3))) uint32_t*>(
            reinterpret_cast<uintptr_t>(l));
    const __attribute__((address_space(1))) uint32_t* gp =
        reinterpret_cast<const __attribute__((address_space(1))) uint32_t*>(
            reinterpret_cast<uintptr_t>(g));
    __builtin_amdgcn_global_load_lds(gp, lp, 16, 0, 0);
}

// ---------------------------------------------------------------------------
// Transpose + fp32->bf16:  in [nmat][R][C] f32 -> out [nmat][C][R] bf16
// ---------------------------------------------------------------------------
__global__ __launch_bounds__(256) void transpose_cvt(
    const float* __restrict__ in, ushort_t* __restrict__ out, int R, int C)
{
    __shared__ float tile[32][33];
    const size_t matoff = (size_t)blockIdx.z * R * C;
    const float* src = in + matoff;
    ushort_t* dst = out + matoff;
    const int r0 = blockIdx.y * 32, c0 = blockIdx.x * 32;
    const int tid = threadIdx.x;
    const int lr = tid >> 3;
    const int lc = (tid & 7) * 4;
    float4 v = *(const float4*)(src + (size_t)(r0 + lr) * C + c0 + lc);
    tile[lr][lc+0] = v.x; tile[lr][lc+1] = v.y;
    tile[lr][lc+2] = v.z; tile[lr][lc+3] = v.w;
    __syncthreads();
    ushort4 o;
    o.x = f2bf(tile[lc+0][lr]);
    o.y = f2bf(tile[lc+1][lr]);
    o.z = f2bf(tile[lc+2][lr]);
    o.w = f2bf(tile[lc+3][lr]);
    *(ushort4*)(dst + (size_t)(c0 + lr) * R + r0 + lc) = o;
}

// ---------------------------------------------------------------------------
// Gating phase 1 + x fp32->bf16 conversion. One wave/token. No atomics.
// ---------------------------------------------------------------------------
__global__ __launch_bounds__(256) void gating_kernel(
    const float* __restrict__ x, const float* __restrict__ gw,
    const float* __restrict__ gb,
    int* __restrict__ eidx, float* __restrict__ gsel, ushort_t* __restrict__ xbf)
{
    const int wave = threadIdx.x >> 6;
    const int lane = threadIdx.x & 63;
    const int t = blockIdx.x * 4 + wave;
    const float* xr = x + (size_t)t * D_;
    ushort_t* xbr = xbf + (size_t)t * D_;

    float acc[E_];
    #pragma unroll
    for (int e = 0; e < E_; ++e) acc[e] = 0.f;

    #pragma unroll
    for (int j = 0; j < 4; ++j) {
        const int d = j * 256 + lane * 4;
        float4 xv = *(const float4*)(xr + d);
        ushort4 o;
        o.x = f2bf(xv.x); o.y = f2bf(xv.y); o.z = f2bf(xv.z); o.w = f2bf(xv.w);
        *(ushort4*)(xbr + d) = o;
        const float* gr = gw + (size_t)d * E_;
        float xs[4] = {xv.x, xv.y, xv.z, xv.w};
        #pragma unroll
        for (int c = 0; c < 4; ++c) {
            float4 g0 = *(const float4*)(gr + c * 8);
            float4 g1 = *(const float4*)(gr + c * 8 + 4);
            acc[0] += xs[c] * g0.x; acc[1] += xs[c] * g0.y;
            acc[2] += xs[c] * g0.z; acc[3] += xs[c] * g0.w;
            acc[4] += xs[c] * g1.x; acc[5] += xs[c] * g1.y;
            acc[6] += xs[c] * g1.z; acc[7] += xs[c] * g1.w;
        }
    }
    #pragma unroll
    for (int s = 1; s < 64; s <<= 1) {
        #pragma unroll
        for (int e = 0; e < E_; ++e)
            acc[e] += __shfl_xor(acc[e], s, 64);
    }
    if (lane == 0) {
        float v[E_];
        #pragma unroll
        for (int e = 0; e < E_; ++e) v[e] = acc[e] + gb[e];
        int i0 = 0;
        #pragma unroll
        for (int e = 1; e < E_; ++e) if (v[e] > v[i0]) i0 = e;
        int i1 = (i0 == 0) ? 1 : 0;
        #pragma unroll
        for (int e = 0; e < E_; ++e) if (e != i0 && v[e] > v[i1]) i1 = e;
        float g0 = 1.f / (1.f + expf(v[i1] - v[i0]));
        eidx[t] = i0 | (i1 << 8);
        gsel[t] = g0;
    }
}

// ---------------------------------------------------------------------------
// Gating phase 2: bucketize (8 global atomics/block) + record per-token
// (expert,pos) pair packed into tpos for the gather-combine.
// ---------------------------------------------------------------------------
__global__ __launch_bounds__(256) void bucket_kernel(
    const int* __restrict__ eidx, const float* __restrict__ gsel,
    int* __restrict__ counts, int* __restrict__ btok, float* __restrict__ bgate,
    uint32_t* __restrict__ tpos)
{
    __shared__ int lcnt[E_];
    __shared__ int lbase[E_];
    const int tid = threadIdx.x;
    if (tid < E_) lcnt[tid] = 0;
    __syncthreads();
    const int t = blockIdx.x * 256 + tid;
    const int pk = eidx[t];
    const float g0 = gsel[t];
    const int i0 = pk & 0xff, i1 = (pk >> 8) & 0xff;
    const int p0 = atomicAdd(&lcnt[i0], 1);
    const int p1 = atomicAdd(&lcnt[i1], 1);
    __syncthreads();
    if (tid < E_) lbase[tid] = atomicAdd(&counts[tid], lcnt[tid]);
    __syncthreads();
    const int q0 = lbase[i0] + p0, q1 = lbase[i1] + p1;
    btok[i0 * T_ + q0] = t; bgate[i0 * T_ + q0] = g0;
    btok[i1 * T_ + q1] = t; bgate[i1 * T_ + q1] = 1.f - g0;
    // pack (expert:3, pos:13) x2 — pos < T_ = 8192 fits 13 bits
    tpos[t] = (uint32_t)((i0 << 13) | q0) | ((uint32_t)((i1 << 13) | q1) << 16);
}

__global__ void prefix_kernel(const int* __restrict__ counts, int* __restrict__ offsets)
{
    if (threadIdx.x == 0 && blockIdx.x == 0) {
        int s = 0;
        for (int e = 0; e < E_; ++e) { offsets[e] = s; s += counts[e]; }
    }
}

// ---------------------------------------------------------------------------
// Layer 1: gathered xbf [n_e,1024] @ W1t[e] ([H][D]) -> gelu -> hbuf bf16
// 128x128 tile, BK=64, global_load_lds staging, XOR-swizzled LDS.
// grid: (64, H/128=4, E)
// ---------------------------------------------------------------------------
__global__ __launch_bounds__(256) void mlp1_kernel(
    const ushort_t* __restrict__ xbf, const ushort_t* __restrict__ w1t,
    const float* __restrict__ b1,
    const int* __restrict__ counts, const int* __restrict__ offsets,
    const int* __restrict__ btok, ushort_t* __restrict__ hbuf)
{
    const int e   = blockIdx.z;
    const int n_e = counts[e];
    const int m0  = blockIdx.x * 128;
    if (m0 >= n_e) return;
    const int n0  = blockIdx.y * 128;
    const int off = offsets[e];

    __shared__ ushort_t As[128 * 64];
    __shared__ ushort_t Bs[128 * 64];

    const int tid  = threadIdx.x;
    const int lane = tid & 63;
    const int wave = tid >> 6;

    const int srow = tid >> 3;                    // 0..31
    const int cg   = (tid & 7) ^ (srow & 7);      // swizzled global col group

    const ushort_t* aptr[4];
    #pragma unroll
    for (int i = 0; i < 4; ++i) {
        int m = m0 + i * 32 + srow;
        int tok = btok[e * T_ + (m < n_e ? m : n_e - 1)];
        aptr[i] = xbf + (size_t)tok * D_ + cg * 8;
    }
    const ushort_t* w1e = w1t + (size_t)e * (H_ * D_);
    const ushort_t* bptr[4];
    #pragma unroll
    for (int i = 0; i < 4; ++i)
        bptr[i] = w1e + (size_t)(n0 + i * 32 + srow) * D_ + cg * 8;

    char* aldst = (char*)As + (wave << 10);
    char* bldst = (char*)Bs + (wave << 10);

    const int fm   = lane & 15;
    const int quad = lane >> 4;
    const int wm   = (wave & 1) * 64;
    const int wn   = (wave >> 1) * 64;

    f32x4 acc[4][4];
    #pragma unroll
    for (int i = 0; i < 4; ++i)
        #pragma unroll
        for (int j = 0; j < 4; ++j)
            { acc[i][j][0]=0.f; acc[i][j][1]=0.f; acc[i][j][2]=0.f; acc[i][j][3]=0.f; }

    for (int k0 = 0; k0 < D_; k0 += 64) {
        #pragma unroll
        for (int i = 0; i < 4; ++i)
            gld_lds16(aptr[i] + k0, aldst + (i << 12));
        #pragma unroll
        for (int i = 0; i < 4; ++i)
            gld_lds16(bptr[i] + k0, bldst + (i << 12));
        __syncthreads();
        #pragma unroll
        for (int kk = 0; kk < 2; ++kk) {
            const int grp = kk * 4 + quad;
            bf16x8 af[4], bfr[4];
            #pragma unroll
            for (int i = 0; i < 4; ++i) {
                int ra = wm + i * 16 + fm;
                af[i]  = *(const bf16x8*)((const char*)As + ra * 128 + ((grp ^ (ra & 7)) << 4));
                int rb = wn + i * 16 + fm;
                bfr[i] = *(const bf16x8*)((const char*)Bs + rb * 128 + ((grp ^ (rb & 7)) << 4));
            }
            #pragma unroll
            for (int i = 0; i < 4; ++i)
                #pragma unroll
                for (int j = 0; j < 4; ++j)
                    acc[i][j] = __builtin_amdgcn_mfma_f32_16x16x32_bf16(af[i], bfr[j], acc[i][j], 0, 0, 0);
        }
        __syncthreads();
    }

    float bcol[4];
    #pragma unroll
    for (int j = 0; j < 4; ++j)
        bcol[j] = b1[e * H_ + n0 + wn + j * 16 + fm];
    #pragma unroll
    for (int i = 0; i < 4; ++i) {
        #pragma unroll
        for (int r = 0; r < 4; ++r) {
            int m = m0 + wm + i * 16 + quad * 4 + r;
            if (m >= n_e) continue;
            ushort_t* hrow = hbuf + (size_t)(off + m) * H_ + n0;
            #pragma unroll
            for (int j = 0; j < 4; ++j)
                hrow[wn + j * 16 + fm] = f2bf(gelu_exact(acc[i][j][r] + bcol[j]));
        }
    }
}

// ---------------------------------------------------------------------------
// Layer 2: hbuf [n_e,512] @ W2t[e] ([D][H]) -> (acc+b2)*gate -> obuf bf16
// PLAIN stores (no atomics) — combine_kernel does the 2-way gather-sum.
// grid: (64, D/128=8, E)
// ---------------------------------------------------------------------------
__global__ __launch_bounds__(256) void mlp2_kernel(
    const ushort_t* __restrict__ hbuf, const ushort_t* __restrict__ w2t,
    const float* __restrict__ b2,
    const int* __restrict__ counts, const int* __restrict__ offsets,
    const float* __restrict__ bgate, ushort_t* __restrict__ obuf)
{
    const int e   = blockIdx.z;
    const int n_e = counts[e];
    const int m0  = blockIdx.x * 128;
    if (m0 >= n_e) return;
    const int n0  = blockIdx.y * 128;
    const int off = offsets[e];

    __shared__ ushort_t As[128 * 64];
    __shared__ ushort_t Bs[128 * 64];

    const int tid  = threadIdx.x;
    const int lane = tid & 63;
    const int wave = tid >> 6;

    const int srow = tid >> 3;
    const int cg   = (tid & 7) ^ (srow & 7);

    const ushort_t* aptr[4];
    #pragma unroll
    for (int i = 0; i < 4; ++i)
        aptr[i] = hbuf + (size_t)(off + m0 + i * 32 + srow) * H_ + cg * 8;  // slack rows ok
    const ushort_t* w2e = w2t + (size_t)e * (D_ * H_);
    const ushort_t* bptr[4];
    #pragma unroll
    for (int i = 0; i < 4; ++i)
        bptr[i] = w2e + (size_t)(n0 + i * 32 + srow) * H_ + cg * 8;

    char* aldst = (char*)As + (wave << 10);
    char* bldst = (char*)Bs + (wave << 10);

    const int fm   = lane & 15;
    const int quad = lane >> 4;
    const int wm   = (wave & 1) * 64;
    const int wn   = (wave >> 1) * 64;

    f32x4 acc[4][4];
    #pragma unroll
    for (int i = 0; i < 4; ++i)
        #pragma unroll
        for (int j = 0; j < 4; ++j)
            { acc[i][j][0]=0.f; acc[i][j][1]=0.f; acc[i][j][2]=0.f; acc[i][j][3]=0.f; }

    for (int k0 = 0; k0 < H_; k0 += 64) {
        #pragma unroll
        for (int i = 0; i < 4; ++i)
            gld_lds16(aptr[i] + k0, aldst + (i << 12));
        #pragma unroll
        for (int i = 0; i < 4; ++i)
            gld_lds16(bptr[i] + k0, bldst + (i << 12));
        __syncthreads();
        #pragma unroll
        for (int kk = 0; kk < 2; ++kk) {
            const int grp = kk * 4 + quad;
            bf16x8 af[4], bfr[4];
            #pragma unroll
            for (int i = 0; i < 4; ++i) {
                int ra = wm + i * 16 + fm;
                af[i]  = *(const bf16x8*)((const char*)As + ra * 128 + ((grp ^ (ra & 7)) << 4));
                int rb = wn + i * 16 + fm;
                bfr[i] = *(const bf16x8*)((const char*)Bs + rb * 128 + ((grp ^ (rb & 7)) << 4));
            }
            #pragma unroll
            for (int i = 0; i < 4; ++i)
                #pragma unroll
                for (int j = 0; j < 4; ++j)
                    acc[i][j] = __builtin_amdgcn_mfma_f32_16x16x32_bf16(af[i], bfr[j], acc[i][j], 0, 0, 0);
        }
        __syncthreads();
    }

    float bcol[4];
    #pragma unroll
    for (int j = 0; j < 4; ++j)
        bcol[j] = b2[e * D_ + n0 + wn + j * 16 + fm];
    #pragma unroll
    for (int i = 0; i < 4; ++i) {
        #pragma unroll
        for (int r = 0; r < 4; ++r) {
            int m = m0 + wm + i * 16 + quad * 4 + r;
            if (m >= n_e) continue;
            float g = bgate[e * T_ + m];
            ushort_t* orow = obuf + (size_t)(off + m) * D_ + n0;
            #pragma unroll
            for (int j = 0; j < 4; ++j)
                orow[wn + j * 16 + fm] = f2bf((acc[i][j][r] + bcol[j]) * g);
        }
    }
}

// ---------------------------------------------------------------------------
// Combine: out[t] = obuf[slot0(t)] + obuf[slot1(t)].  2 tokens per block.
// ---------------------------------------------------------------------------
__global__ __launch_bounds__(256) void combine_kernel(
    const ushort_t* __restrict__ obuf, const uint32_t* __restrict__ tpos,
    const int* __restrict__ offsets, float* __restrict__ out)
{
    const int tid = threadIdx.x;
    const int t = blockIdx.x * 2 + (tid >> 7);
    const int c = (tid & 127) * 8;
    const uint32_t pk = tpos[t];
    const int e0 = (pk >> 13) & 7, p0 = pk & 0x1fff;
    const int e1 = (pk >> 29) & 7, p1 = (pk >> 16) & 0x1fff;
    const size_t s0 = (size_t)(offsets[e0] + p0) * D_ + c;
    const size_t s1 = (size_t)(offsets[e1] + p1) * D_ + c;
    bf16x8 a = *(const bf16x8*)(obuf + s0);
    bf16x8 b = *(const bf16x8*)(obuf + s1);
    float4 o0, o1;
    o0.x = (float)a[0] + (float)b[0];
    o0.y = (float)a[1] + (float)b[1];
    o0.z = (float)a[2] + (float)b[2];
    o0.w = (float)a[3] + (float)b[3];
    o1.x = (float)a[4] + (float)b[4];
    o1.y = (float)a[5] + (float)b[5];
    o1.z = (float)a[6] + (float)b[6];
    o1.w = (float)a[7] + (float)b[7];
    float* orow = out + (size_t)t * D_ + c;
    *(float4*)(orow)     = o0;
    *(float4*)(orow + 4) = o1;
}

// ---------------------------------------------------------------------------
extern "C" void kernel_launch(void* const* d_in, const int* in_sizes, int n_in,
                              void* d_out, int out_size, void* d_ws, size_t ws_size,
                              hipStream_t stream)
{
    const float* x  = (const float*)d_in[0];
    const float* gw = (const float*)d_in[1];
    const float* gb = (const float*)d_in[2];
    const float* w1 = (const float*)d_in[3];
    const float* b1 = (const float*)d_in[4];
    const float* w2 = (const float*)d_in[5];
    const float* b2 = (const float*)d_in[6];
    float* out = (float*)d_out;

    // workspace layout
    char* ws = (char*)d_ws;
    int*   counts  = (int*)ws;                                   // 8 ints
    int*   offsets = counts + 8;
    int*   btok    = (int*)(ws + 256);                           // E*T ints
    float* bgate   = (float*)(ws + 256 + (size_t)E_*T_*4);
    size_t p = 256 + 2ull * E_ * T_ * 4;
    int*      eidx = (int*)(ws + p);      p += (size_t)T_ * 4;
    float*    gsel = (float*)(ws + p);    p += (size_t)T_ * 4;
    uint32_t* tpos = (uint32_t*)(ws + p); p += (size_t)T_ * 4;
    ushort_t* xbf  = (ushort_t*)(ws + p); p += (size_t)T_*D_*2;      // bf16 x (16 MB)
    ushort_t* w1t  = (ushort_t*)(ws + p); p += (size_t)E_*H_*D_*2;   // bf16 [E][H][D] (8 MB)
    ushort_t* w2t  = (ushort_t*)(ws + p); p += (size_t)E_*D_*H_*2;   // bf16 [E][D][H] (8 MB)
    ushort_t* hbuf = (ushort_t*)(ws + p); p += ((size_t)2*T_+128)*H_*2; // bf16 (16.5 MB)
    ushort_t* obuf = (ushort_t*)(ws + p);                        // bf16 [2T+128][D] (33 MB)

    (void)hipMemsetAsync(counts, 0, 64, stream);

    transpose_cvt<<<dim3(H_/32, D_/32, E_), 256, 0, stream>>>(w1, w1t, D_, H_);
    transpose_cvt<<<dim3(D_/32, H_/32, E_), 256, 0, stream>>>(w2, w2t, H_, D_);
    gating_kernel<<<T_/4, 256, 0, stream>>>(x, gw, gb, eidx, gsel, xbf);
    bucket_kernel<<<T_/256, 256, 0, stream>>>(eidx, gsel, counts, btok, bgate, tpos);
    prefix_kernel<<<1, 64, 0, stream>>>(counts, offsets);
    mlp1_kernel<<<dim3(T_/128, H_/128, E_), 256, 0, stream>>>(
        xbf, w1t, b1, counts, offsets, btok, hbuf);
    mlp2_kernel<<<dim3(T_/128, D_/128, E_), 256, 0, stream>>>(
        hbuf, w2t, b2, counts, offsets, bgate, obuf);
    combine_kernel<<<T_/2, 256, 0, stream>>>(obuf, tpos, offsets, out);
}

// Round 6
// 238.605 us; speedup vs baseline: 1.9424x; 1.1235x over previous
//
#include <hip/hip_runtime.h>
#include <hip/hip_bf16.h>
#include <stdint.h>

#define B_    4
#define L_    2048
#define T_    8192      // B*L tokens
#define D_    1024
#define E_    8
#define H_    512

typedef __bf16  bf16x8 __attribute__((ext_vector_type(8)));
typedef float   f32x4  __attribute__((ext_vector_type(4)));
typedef unsigned short ushort_t;

__device__ __forceinline__ ushort_t f2bf(float f) {
    union { float f; unsigned u; } v; v.f = f;
    unsigned u = v.u;
    unsigned r = (u + 0x7fffu + ((u >> 16) & 1u)) >> 16;   // RNE
    return (ushort_t)r;
}

__device__ __forceinline__ float gelu_exact(float v) {
    return 0.5f * v * (1.0f + erff(v * 0.70710678118654752f));
}

// async global->LDS, 16B per lane; LDS dest = wave-uniform base + lane*16
__device__ __forceinline__ void gld_lds16(const void* g, void* l) {
    __attribute__((address_space(3))) uint32_t* lp =
        reinterpret_cast<__attribute__((address_space(3))) uint32_t*>(
            reinterpret_cast<uintptr_t>(l));
    const __attribute__((address_space(1))) uint32_t* gp =
        reinterpret_cast<const __attribute__((address_space(1))) uint32_t*>(
            reinterpret_cast<uintptr_t>(g));
    __builtin_amdgcn_global_load_lds(gp, lp, 16, 0, 0);
}

// ---------------------------------------------------------------------------
// Transpose + fp32->bf16:  in [nmat][R][C] f32 -> out [nmat][C][R] bf16
// ---------------------------------------------------------------------------
__global__ __launch_bounds__(256) void transpose_cvt(
    const float* __restrict__ in, ushort_t* __restrict__ out, int R, int C)
{
    __shared__ float tile[32][33];
    const size_t matoff = (size_t)blockIdx.z * R * C;
    const float* src = in + matoff;
    ushort_t* dst = out + matoff;
    const int r0 = blockIdx.y * 32, c0 = blockIdx.x * 32;
    const int tid = threadIdx.x;
    const int lr = tid >> 3;
    const int lc = (tid & 7) * 4;
    float4 v = *(const float4*)(src + (size_t)(r0 + lr) * C + c0 + lc);
    tile[lr][lc+0] = v.x; tile[lr][lc+1] = v.y;
    tile[lr][lc+2] = v.z; tile[lr][lc+3] = v.w;
    __syncthreads();
    ushort4 o;
    o.x = f2bf(tile[lc+0][lr]);
    o.y = f2bf(tile[lc+1][lr]);
    o.z = f2bf(tile[lc+2][lr]);
    o.w = f2bf(tile[lc+3][lr]);
    *(ushort4*)(dst + (size_t)(c0 + lr) * R + r0 + lc) = o;
}

// ---------------------------------------------------------------------------
// Gating phase 1 + x fp32->bf16 conversion. One wave/token. No atomics.
// ---------------------------------------------------------------------------
__global__ __launch_bounds__(256) void gating_kernel(
    const float* __restrict__ x, const float* __restrict__ gw,
    const float* __restrict__ gb,
    int* __restrict__ eidx, float* __restrict__ gsel, ushort_t* __restrict__ xbf)
{
    const int wave = threadIdx.x >> 6;
    const int lane = threadIdx.x & 63;
    const int t = blockIdx.x * 4 + wave;
    const float* xr = x + (size_t)t * D_;
    ushort_t* xbr = xbf + (size_t)t * D_;

    float acc[E_];
    #pragma unroll
    for (int e = 0; e < E_; ++e) acc[e] = 0.f;

    #pragma unroll
    for (int j = 0; j < 4; ++j) {
        const int d = j * 256 + lane * 4;
        float4 xv = *(const float4*)(xr + d);
        ushort4 o;
        o.x = f2bf(xv.x); o.y = f2bf(xv.y); o.z = f2bf(xv.z); o.w = f2bf(xv.w);
        *(ushort4*)(xbr + d) = o;
        const float* gr = gw + (size_t)d * E_;
        float xs[4] = {xv.x, xv.y, xv.z, xv.w};
        #pragma unroll
        for (int c = 0; c < 4; ++c) {
            float4 g0 = *(const float4*)(gr + c * 8);
            float4 g1 = *(const float4*)(gr + c * 8 + 4);
            acc[0] += xs[c] * g0.x; acc[1] += xs[c] * g0.y;
            acc[2] += xs[c] * g0.z; acc[3] += xs[c] * g0.w;
            acc[4] += xs[c] * g1.x; acc[5] += xs[c] * g1.y;
            acc[6] += xs[c] * g1.z; acc[7] += xs[c] * g1.w;
        }
    }
    #pragma unroll
    for (int s = 1; s < 64; s <<= 1) {
        #pragma unroll
        for (int e = 0; e < E_; ++e)
            acc[e] += __shfl_xor(acc[e], s, 64);
    }
    if (lane == 0) {
        float v[E_];
        #pragma unroll
        for (int e = 0; e < E_; ++e) v[e] = acc[e] + gb[e];
        int i0 = 0;
        #pragma unroll
        for (int e = 1; e < E_; ++e) if (v[e] > v[i0]) i0 = e;
        int i1 = (i0 == 0) ? 1 : 0;
        #pragma unroll
        for (int e = 0; e < E_; ++e) if (e != i0 && v[e] > v[i1]) i1 = e;
        float g0 = 1.f / (1.f + expf(v[i1] - v[i0]));
        eidx[t] = i0 | (i1 << 8);
        gsel[t] = g0;
    }
}

// ---------------------------------------------------------------------------
// Gating phase 2: bucketize (8 global atomics/block) + pack (expert,pos) x2.
// ---------------------------------------------------------------------------
__global__ __launch_bounds__(256) void bucket_kernel(
    const int* __restrict__ eidx, const float* __restrict__ gsel,
    int* __restrict__ counts, int* __restrict__ btok, float* __restrict__ bgate,
    uint32_t* __restrict__ tpos)
{
    __shared__ int lcnt[E_];
    __shared__ int lbase[E_];
    const int tid = threadIdx.x;
    if (tid < E_) lcnt[tid] = 0;
    __syncthreads();
    const int t = blockIdx.x * 256 + tid;
    const int pk = eidx[t];
    const float g0 = gsel[t];
    const int i0 = pk & 0xff, i1 = (pk >> 8) & 0xff;
    const int p0 = atomicAdd(&lcnt[i0], 1);
    const int p1 = atomicAdd(&lcnt[i1], 1);
    __syncthreads();
    if (tid < E_) lbase[tid] = atomicAdd(&counts[tid], lcnt[tid]);
    __syncthreads();
    const int q0 = lbase[i0] + p0, q1 = lbase[i1] + p1;
    btok[i0 * T_ + q0] = t; bgate[i0 * T_ + q0] = g0;
    btok[i1 * T_ + q1] = t; bgate[i1 * T_ + q1] = 1.f - g0;
    tpos[t] = (uint32_t)((i0 << 13) | q0) | ((uint32_t)((i1 << 13) | q1) << 16);
}

__global__ void prefix_kernel(const int* __restrict__ counts, int* __restrict__ offsets)
{
    if (threadIdx.x == 0 && blockIdx.x == 0) {
        int s = 0;
        for (int e = 0; e < E_; ++e) { offsets[e] = s; s += counts[e]; }
    }
}

// ---------------------------------------------------------------------------
// Layer 1: gathered xbf [n_e,1024] @ W1t[e] ([H][D]) -> gelu -> hbuf bf16
// 64x128 tile (M x N), BK=64 — 2x active blocks vs 128x128 for latency hiding.
// LDS: As 8KB + Bs 16KB = 24KB -> up to 6 blocks/CU.
// grid: (T_/64=128, H/128=4, E)
// ---------------------------------------------------------------------------
__global__ __launch_bounds__(256) void mlp1_kernel(
    const ushort_t* __restrict__ xbf, const ushort_t* __restrict__ w1t,
    const float* __restrict__ b1,
    const int* __restrict__ counts, const int* __restrict__ offsets,
    const int* __restrict__ btok, ushort_t* __restrict__ hbuf)
{
    const int e   = blockIdx.z;
    const int n_e = counts[e];
    const int m0  = blockIdx.x * 64;
    if (m0 >= n_e) return;
    const int n0  = blockIdx.y * 128;
    const int off = offsets[e];

    __shared__ ushort_t As[64 * 64];
    __shared__ ushort_t Bs[128 * 64];

    const int tid  = threadIdx.x;
    const int lane = tid & 63;
    const int wave = tid >> 6;

    const int srow = tid >> 3;                    // 0..31
    const int cg   = (tid & 7) ^ (srow & 7);      // swizzled global col group

    const ushort_t* aptr[2];
    #pragma unroll
    for (int i = 0; i < 2; ++i) {
        int m = m0 + i * 32 + srow;
        int tok = btok[e * T_ + (m < n_e ? m : n_e - 1)];
        aptr[i] = xbf + (size_t)tok * D_ + cg * 8;
    }
    const ushort_t* w1e = w1t + (size_t)e * (H_ * D_);
    const ushort_t* bptr[4];
    #pragma unroll
    for (int i = 0; i < 4; ++i)
        bptr[i] = w1e + (size_t)(n0 + i * 32 + srow) * D_ + cg * 8;

    char* aldst = (char*)As + (wave << 10);
    char* bldst = (char*)Bs + (wave << 10);

    const int fm   = lane & 15;
    const int quad = lane >> 4;
    const int wm   = (wave & 1) * 32;     // 2 waves over M=64
    const int wn   = (wave >> 1) * 64;    // 2 waves over N=128

    f32x4 acc[2][4];
    #pragma unroll
    for (int i = 0; i < 2; ++i)
        #pragma unroll
        for (int j = 0; j < 4; ++j)
            { acc[i][j][0]=0.f; acc[i][j][1]=0.f; acc[i][j][2]=0.f; acc[i][j][3]=0.f; }

    for (int k0 = 0; k0 < D_; k0 += 64) {
        #pragma unroll
        for (int i = 0; i < 2; ++i)
            gld_lds16(aptr[i] + k0, aldst + (i << 12));
        #pragma unroll
        for (int i = 0; i < 4; ++i)
            gld_lds16(bptr[i] + k0, bldst + (i << 12));
        __syncthreads();
        #pragma unroll
        for (int kk = 0; kk < 2; ++kk) {
            const int grp = kk * 4 + quad;
            bf16x8 af[2], bfr[4];
            #pragma unroll
            for (int i = 0; i < 2; ++i) {
                int ra = wm + i * 16 + fm;
                af[i]  = *(const bf16x8*)((const char*)As + ra * 128 + ((grp ^ (ra & 7)) << 4));
            }
            #pragma unroll
            for (int j = 0; j < 4; ++j) {
                int rb = wn + j * 16 + fm;
                bfr[j] = *(const bf16x8*)((const char*)Bs + rb * 128 + ((grp ^ (rb & 7)) << 4));
            }
            #pragma unroll
            for (int i = 0; i < 2; ++i)
                #pragma unroll
                for (int j = 0; j < 4; ++j)
                    acc[i][j] = __builtin_amdgcn_mfma_f32_16x16x32_bf16(af[i], bfr[j], acc[i][j], 0, 0, 0);
        }
        __syncthreads();
    }

    float bcol[4];
    #pragma unroll
    for (int j = 0; j < 4; ++j)
        bcol[j] = b1[e * H_ + n0 + wn + j * 16 + fm];
    #pragma unroll
    for (int i = 0; i < 2; ++i) {
        #pragma unroll
        for (int r = 0; r < 4; ++r) {
            int m = m0 + wm + i * 16 + quad * 4 + r;
            if (m >= n_e) continue;
            ushort_t* hrow = hbuf + (size_t)(off + m) * H_ + n0;
            #pragma unroll
            for (int j = 0; j < 4; ++j)
                hrow[wn + j * 16 + fm] = f2bf(gelu_exact(acc[i][j][r] + bcol[j]));
        }
    }
}

// ---------------------------------------------------------------------------
// Layer 2: hbuf [n_e,512] @ W2t[e] ([D][H]) -> (acc+b2)*gate -> obuf bf16
// 64x128 tile, BK=64, plain stores. grid: (128, D/128=8, E)
// ---------------------------------------------------------------------------
__global__ __launch_bounds__(256) void mlp2_kernel(
    const ushort_t* __restrict__ hbuf, const ushort_t* __restrict__ w2t,
    const float* __restrict__ b2,
    const int* __restrict__ counts, const int* __restrict__ offsets,
    const float* __restrict__ bgate, ushort_t* __restrict__ obuf)
{
    const int e   = blockIdx.z;
    const int n_e = counts[e];
    const int m0  = blockIdx.x * 64;
    if (m0 >= n_e) return;
    const int n0  = blockIdx.y * 128;
    const int off = offsets[e];

    __shared__ ushort_t As[64 * 64];
    __shared__ ushort_t Bs[128 * 64];

    const int tid  = threadIdx.x;
    const int lane = tid & 63;
    const int wave = tid >> 6;

    const int srow = tid >> 3;
    const int cg   = (tid & 7) ^ (srow & 7);

    const ushort_t* aptr[2];
    #pragma unroll
    for (int i = 0; i < 2; ++i)
        aptr[i] = hbuf + (size_t)(off + m0 + i * 32 + srow) * H_ + cg * 8;  // slack rows ok
    const ushort_t* w2e = w2t + (size_t)e * (D_ * H_);
    const ushort_t* bptr[4];
    #pragma unroll
    for (int i = 0; i < 4; ++i)
        bptr[i] = w2e + (size_t)(n0 + i * 32 + srow) * H_ + cg * 8;

    char* aldst = (char*)As + (wave << 10);
    char* bldst = (char*)Bs + (wave << 10);

    const int fm   = lane & 15;
    const int quad = lane >> 4;
    const int wm   = (wave & 1) * 32;
    const int wn   = (wave >> 1) * 64;

    f32x4 acc[2][4];
    #pragma unroll
    for (int i = 0; i < 2; ++i)
        #pragma unroll
        for (int j = 0; j < 4; ++j)
            { acc[i][j][0]=0.f; acc[i][j][1]=0.f; acc[i][j][2]=0.f; acc[i][j][3]=0.f; }

    for (int k0 = 0; k0 < H_; k0 += 64) {
        #pragma unroll
        for (int i = 0; i < 2; ++i)
            gld_lds16(aptr[i] + k0, aldst + (i << 12));
        #pragma unroll
        for (int i = 0; i < 4; ++i)
            gld_lds16(bptr[i] + k0, bldst + (i << 12));
        __syncthreads();
        #pragma unroll
        for (int kk = 0; kk < 2; ++kk) {
            const int grp = kk * 4 + quad;
            bf16x8 af[2], bfr[4];
            #pragma unroll
            for (int i = 0; i < 2; ++i) {
                int ra = wm + i * 16 + fm;
                af[i]  = *(const bf16x8*)((const char*)As + ra * 128 + ((grp ^ (ra & 7)) << 4));
            }
            #pragma unroll
            for (int j = 0; j < 4; ++j) {
                int rb = wn + j * 16 + fm;
                bfr[j] = *(const bf16x8*)((const char*)Bs + rb * 128 + ((grp ^ (rb & 7)) << 4));
            }
            #pragma unroll
            for (int i = 0; i < 2; ++i)
                #pragma unroll
                for (int j = 0; j < 4; ++j)
                    acc[i][j] = __builtin_amdgcn_mfma_f32_16x16x32_bf16(af[i], bfr[j], acc[i][j], 0, 0, 0);
        }
        __syncthreads();
    }

    float bcol[4];
    #pragma unroll
    for (int j = 0; j < 4; ++j)
        bcol[j] = b2[e * D_ + n0 + wn + j * 16 + fm];
    #pragma unroll
    for (int i = 0; i < 2; ++i) {
        #pragma unroll
        for (int r = 0; r < 4; ++r) {
            int m = m0 + wm + i * 16 + quad * 4 + r;
            if (m >= n_e) continue;
            float g = bgate[e * T_ + m];
            ushort_t* orow = obuf + (size_t)(off + m) * D_ + n0;
            #pragma unroll
            for (int j = 0; j < 4; ++j)
                orow[wn + j * 16 + fm] = f2bf((acc[i][j][r] + bcol[j]) * g);
        }
    }
}

// ---------------------------------------------------------------------------
// Combine: out[t] = obuf[slot0(t)] + obuf[slot1(t)].  2 tokens per block.
// ---------------------------------------------------------------------------
__global__ __launch_bounds__(256) void combine_kernel(
    const ushort_t* __restrict__ obuf, const uint32_t* __restrict__ tpos,
    const int* __restrict__ offsets, float* __restrict__ out)
{
    const int tid = threadIdx.x;
    const int t = blockIdx.x * 2 + (tid >> 7);
    const int c = (tid & 127) * 8;
    const uint32_t pk = tpos[t];
    const int e0 = (pk >> 13) & 7, p0 = pk & 0x1fff;
    const int e1 = (pk >> 29) & 7, p1 = (pk >> 16) & 0x1fff;
    const size_t s0 = (size_t)(offsets[e0] + p0) * D_ + c;
    const size_t s1 = (size_t)(offsets[e1] + p1) * D_ + c;
    bf16x8 a = *(const bf16x8*)(obuf + s0);
    bf16x8 b = *(const bf16x8*)(obuf + s1);
    float4 o0, o1;
    o0.x = (float)a[0] + (float)b[0];
    o0.y = (float)a[1] + (float)b[1];
    o0.z = (float)a[2] + (float)b[2];
    o0.w = (float)a[3] + (float)b[3];
    o1.x = (float)a[4] + (float)b[4];
    o1.y = (float)a[5] + (float)b[5];
    o1.z = (float)a[6] + (float)b[6];
    o1.w = (float)a[7] + (float)b[7];
    float* orow = out + (size_t)t * D_ + c;
    *(float4*)(orow)     = o0;
    *(float4*)(orow + 4) = o1;
}

// ---------------------------------------------------------------------------
extern "C" void kernel_launch(void* const* d_in, const int* in_sizes, int n_in,
                              void* d_out, int out_size, void* d_ws, size_t ws_size,
                              hipStream_t stream)
{
    const float* x  = (const float*)d_in[0];
    const float* gw = (const float*)d_in[1];
    const float* gb = (const float*)d_in[2];
    const float* w1 = (const float*)d_in[3];
    const float* b1 = (const float*)d_in[4];
    const float* w2 = (const float*)d_in[5];
    const float* b2 = (const float*)d_in[6];
    float* out = (float*)d_out;

    // workspace layout
    char* ws = (char*)d_ws;
    int*   counts  = (int*)ws;                                   // 8 ints
    int*   offsets = counts + 8;
    int*   btok    = (int*)(ws + 256);                           // E*T ints
    float* bgate   = (float*)(ws + 256 + (size_t)E_*T_*4);
    size_t p = 256 + 2ull * E_ * T_ * 4;
    int*      eidx = (int*)(ws + p);      p += (size_t)T_ * 4;
    float*    gsel = (float*)(ws + p);    p += (size_t)T_ * 4;
    uint32_t* tpos = (uint32_t*)(ws + p); p += (size_t)T_ * 4;
    ushort_t* xbf  = (ushort_t*)(ws + p); p += (size_t)T_*D_*2;      // bf16 x (16 MB)
    ushort_t* w1t  = (ushort_t*)(ws + p); p += (size_t)E_*H_*D_*2;   // bf16 [E][H][D] (8 MB)
    ushort_t* w2t  = (ushort_t*)(ws + p); p += (size_t)E_*D_*H_*2;   // bf16 [E][D][H] (8 MB)
    ushort_t* hbuf = (ushort_t*)(ws + p); p += ((size_t)2*T_+128)*H_*2; // bf16 (16.5 MB)
    ushort_t* obuf = (ushort_t*)(ws + p);                        // bf16 [2T+128][D] (33 MB)

    (void)hipMemsetAsync(counts, 0, 64, stream);

    transpose_cvt<<<dim3(H_/32, D_/32, E_), 256, 0, stream>>>(w1, w1t, D_, H_);
    transpose_cvt<<<dim3(D_/32, H_/32, E_), 256, 0, stream>>>(w2, w2t, H_, D_);
    gating_kernel<<<T_/4, 256, 0, stream>>>(x, gw, gb, eidx, gsel, xbf);
    bucket_kernel<<<T_/256, 256, 0, stream>>>(eidx, gsel, counts, btok, bgate, tpos);
    prefix_kernel<<<1, 64, 0, stream>>>(counts, offsets);
    mlp1_kernel<<<dim3(T_/64, H_/128, E_), 256, 0, stream>>>(
        xbf, w1t, b1, counts, offsets, btok, hbuf);
    mlp2_kernel<<<dim3(T_/64, D_/128, E_), 256, 0, stream>>>(
        hbuf, w2t, b2, counts, offsets, bgate, obuf);
    combine_kernel<<<T_/2, 256, 0, stream>>>(obuf, tpos, offsets, out);
}